// Round 3
// baseline (443.508 us; speedup 1.0000x reference)
//
#include <hip/hip_runtime.h>

#define RES 512
#define PS 64
#define NPATCH 512
#define BATCH 16
#define NTILE 8                              // 8x8 tiles of 64x64 per image
#define NLISTS (BATCH * NTILE * NTILE)       // 1024 (b, tile) lists
#define LIST_CAP 512                         // absolute worst case: all patches of a batch

// ---- kernel 1: bin each patch into the (<=4) 64x64 output tiles it touches ----
// Entry packs (k, ch, cw) so the gather pass never re-reads coords.
__global__ void bin_kernel(const int* __restrict__ coords,
                           int* __restrict__ cnt,
                           unsigned* __restrict__ lists) {
    int p = blockIdx.x * blockDim.x + threadIdx.x;   // b*NPATCH + k
    if (p >= BATCH * NPATCH) return;
    int b = p >> 9;                                  // NPATCH = 512
    int k = p & (NPATCH - 1);
    int ch = coords[2 * p + 0];                      // [0,448]
    int cw = coords[2 * p + 1];
    unsigned pack = (unsigned)k | ((unsigned)ch << 10) | ((unsigned)cw << 19);
    int tr0 = ch >> 6, tr1 = (ch + PS - 1) >> 6;     // <= 7 always
    int tc0 = cw >> 6, tc1 = (cw + PS - 1) >> 6;
    for (int tr = tr0; tr <= tr1; ++tr) {
        for (int tc = tc0; tc <= tc1; ++tc) {
            int list = b * (NTILE * NTILE) + tr * NTILE + tc;
            int idx = atomicAdd(&cnt[list], 1);      // idx < 512 guaranteed
            lists[list * LIST_CAP + idx] = pack;
        }
    }
}

// ---- kernel 2: gather. One block per (b, 64x64 tile). Thread owns 16
// consecutive rows x 1 column. Sums and overlap counts in registers;
// input read exactly once device-wide, output written exactly once. ----
__global__ __launch_bounds__(256) void gather_kernel(
        const float* __restrict__ logits,
        const int* __restrict__ cnt,
        const unsigned* __restrict__ lists,
        float* __restrict__ out) {
    __shared__ unsigned sl[LIST_CAP];

    int blk = blockIdx.x;                    // b*64 + tr*8 + tc
    int b  = blk >> 6;
    int tr = (blk >> 3) & 7;
    int tc = blk & 7;

    int n = cnt[blk];                        // <= 512 by construction
    for (int i = threadIdx.x; i < n; i += 256) sl[i] = lists[blk * LIST_CAP + i];
    __syncthreads();

    int c_local = threadIdx.x & 63;          // column within tile (lane id)
    int rblock  = threadIdx.x >> 6;          // 0..3: which 16-row band
    int gcol  = tc * 64 + c_local;           // global column
    int grow0 = tr * 64 + rblock * 16;       // first of my 16 consecutive rows

    float sum[16];
    int   cc[16];
#pragma unroll
    for (int j = 0; j < 16; ++j) { sum[j] = 0.f; cc[j] = 0; }

    for (int i = 0; i < n; ++i) {
        unsigned e = sl[i];                  // LDS broadcast — no bank conflict
        int k  = e & 1023;
        int ch = (e >> 10) & 511;
        int cw = (e >> 19) & 511;
        int dc = gcol - cw;                  // column within patch
        if ((unsigned)dc < 64u) {            // contiguous active lane range
            const float* pbase = logits + ((size_t)(b * NPATCH + k) << 12) + dc;
            int dr0 = grow0 - ch;            // row-in-patch of my first row
#pragma unroll
            for (int j = 0; j < 16; ++j) {   // static indices: stay in VGPRs
                int dr = dr0 + j;
                if ((unsigned)dr < 64u) {
                    sum[j] += pbase[dr << 6];
                    cc[j]  += 1;
                }
            }
        }
    }

    size_t obase = ((size_t)b * RES + grow0) * RES + gcol;
#pragma unroll
    for (int j = 0; j < 16; ++j) {
        float v = sum[j] / fmaxf((float)cc[j], 1.0f);
        __builtin_nontemporal_store(v, &out[obase + (size_t)j * RES]);
    }
}

extern "C" void kernel_launch(void* const* d_in, const int* in_sizes, int n_in,
                              void* d_out, int out_size, void* d_ws, size_t ws_size,
                              hipStream_t stream) {
    const float* logits = (const float*)d_in[0];  // [16,512,1,64,64] f32
    const int*   coords = (const int*)d_in[1];    // [16,512,2] i32
    float* out = (float*)d_out;                   // [16,1,512,512] f32

    // ws layout: [0,4KB) list counters | [4KB, 4KB+2MB) packed lists
    int*      cnt   = (int*)d_ws;
    unsigned* lists = (unsigned*)((char*)d_ws + 4096);

    hipMemsetAsync(cnt, 0, NLISTS * sizeof(int), stream);   // graph-capturable
    bin_kernel<<<(BATCH * NPATCH + 255) / 256, 256, 0, stream>>>(coords, cnt, lists);
    gather_kernel<<<NLISTS, 256, 0, stream>>>(logits, cnt, lists, out);
}

// Round 4
// 288.587 us; speedup vs baseline: 1.5368x; 1.5368x over previous
//
#include <hip/hip_runtime.h>

#define RES 512
#define PS 64
#define NPATCH 512
#define BATCH 16
#define NTILE 8                              // 8x8 tiles of 64x64 per image
#define NLISTS (BATCH * NTILE * NTILE)       // 1024 (b, tile) lists
#define LIST_CAP 512                         // worst case: all patches of a batch

// ---- kernel 1: bin each patch into the (<=4) 64x64 output tiles it touches ----
__global__ void bin_kernel(const int* __restrict__ coords,
                           int* __restrict__ cnt,
                           unsigned* __restrict__ lists) {
    int p = blockIdx.x * blockDim.x + threadIdx.x;   // b*NPATCH + k
    if (p >= BATCH * NPATCH) return;
    int b = p >> 9;
    int k = p & (NPATCH - 1);
    int ch = coords[2 * p + 0];                      // [0,448]
    int cw = coords[2 * p + 1];
    unsigned pack = (unsigned)k | ((unsigned)ch << 10) | ((unsigned)cw << 19);
    int tr0 = ch >> 6, tr1 = (ch + PS - 1) >> 6;
    int tc0 = cw >> 6, tc1 = (cw + PS - 1) >> 6;
    for (int tr = tr0; tr <= tr1; ++tr) {
        for (int tc = tc0; tc <= tc1; ++tc) {
            int list = b * (NTILE * NTILE) + tr * NTILE + tc;
            int idx = atomicAdd(&cnt[list], 1);      // idx < 512 guaranteed
            lists[list * LIST_CAP + idx] = pack;
        }
    }
}

// ---- kernel 2: gather. One block per (b, tile, 16-row band): 4096 blocks.
// Thread owns 4 consecutive rows x 1 column. Sums/counts in registers;
// logits read exactly once device-wide, output written exactly once. ----
__global__ __launch_bounds__(256) void gather_kernel(
        const float* __restrict__ logits,
        const int* __restrict__ cnt,
        const unsigned* __restrict__ lists,
        float* __restrict__ out) {
    __shared__ unsigned sl[LIST_CAP];

    int blk  = blockIdx.x;
    int band = blk & 3;                      // 16-row band within the tile
    int list = blk >> 2;                     // b*64 + tr*8 + tc
    int b  = list >> 6;
    int tr = (list >> 3) & 7;
    int tc = list & 7;

    int n = cnt[list];                       // <= 512 by construction
    for (int i = threadIdx.x; i < n; i += 256) sl[i] = lists[list * LIST_CAP + i];
    __syncthreads();

    int lane = threadIdx.x & 63;             // column within tile
    int w    = threadIdx.x >> 6;             // wave id: 4-row group in band
    int gcol = tc * 64 + lane;               // global column
    int row0 = tr * 64 + band * 16 + w * 4;  // first of my 4 rows

    float sum[4];
    int   cc[4];
#pragma unroll
    for (int j = 0; j < 4; ++j) { sum[j] = 0.f; cc[j] = 0; }

    for (int i = 0; i < n; ++i) {
        unsigned e = sl[i];                  // LDS broadcast (uniform)
        int ch = (e >> 10) & 511;
        int dr0 = row0 - ch;                 // wave-uniform
        if (dr0 < -3 || dr0 > 63) continue;  // my 4 rows miss this patch
        int k  = e & 1023;
        int cw = (e >> 19) & 511;
        int dc = gcol - cw;                  // column within patch, per-lane
        if ((unsigned)dc < 64u) {            // contiguous active lane range
            const float* pbase = logits + ((size_t)(b * NPATCH + k) << 12) + dc;
#pragma unroll
            for (int j = 0; j < 4; ++j) {    // static indices: stay in VGPRs
                int dr = dr0 + j;
                if ((unsigned)dr < 64u) {
                    sum[j] += pbase[dr << 6];
                    cc[j]  += 1;
                }
            }
        }
    }

    size_t obase = ((size_t)b * RES + row0) * RES + gcol;
#pragma unroll
    for (int j = 0; j < 4; ++j) {
        float v = sum[j] / fmaxf((float)cc[j], 1.0f);
        __builtin_nontemporal_store(v, &out[obase + (size_t)j * RES]);
    }
}

extern "C" void kernel_launch(void* const* d_in, const int* in_sizes, int n_in,
                              void* d_out, int out_size, void* d_ws, size_t ws_size,
                              hipStream_t stream) {
    const float* logits = (const float*)d_in[0];  // [16,512,1,64,64] f32
    const int*   coords = (const int*)d_in[1];    // [16,512,2] i32
    float* out = (float*)d_out;                   // [16,1,512,512] f32

    // ws layout: [0,4KB) list counters | [4KB, 4KB+2MB) packed lists
    int*      cnt   = (int*)d_ws;
    unsigned* lists = (unsigned*)((char*)d_ws + 4096);

    hipMemsetAsync(cnt, 0, NLISTS * sizeof(int), stream);
    bin_kernel<<<(BATCH * NPATCH + 255) / 256, 256, 0, stream>>>(coords, cnt, lists);
    gather_kernel<<<NLISTS * 4, 256, 0, stream>>>(logits, cnt, lists, out);
}

// Round 5
// 219.657 us; speedup vs baseline: 2.0191x; 1.3138x over previous
//
#include <hip/hip_runtime.h>

#define RES 512
#define PS 64
#define NPATCH 512
#define BATCH 16
#define NTILE 8                              // 8x8 tiles of 64x64 per image
#define NLISTS (BATCH * NTILE * NTILE)       // 1024 (b, tile) lists
#define LIST_CAP 512                         // worst case: all patches of a batch

// ---- kernel 1: bin each patch into the (<=4) 64x64 output tiles it touches ----
__global__ void bin_kernel(const int* __restrict__ coords,
                           int* __restrict__ cnt,
                           unsigned* __restrict__ lists) {
    int p = blockIdx.x * blockDim.x + threadIdx.x;   // b*NPATCH + k
    if (p >= BATCH * NPATCH) return;
    int b = p >> 9;
    int k = p & (NPATCH - 1);
    int ch = coords[2 * p + 0];                      // [0,448]
    int cw = coords[2 * p + 1];
    unsigned pack = (unsigned)k | ((unsigned)ch << 10) | ((unsigned)cw << 19);
    int tr0 = ch >> 6, tr1 = (ch + PS - 1) >> 6;
    int tc0 = cw >> 6, tc1 = (cw + PS - 1) >> 6;
    for (int tr = tr0; tr <= tr1; ++tr) {
        for (int tc = tc0; tc <= tc1; ++tc) {
            int list = b * (NTILE * NTILE) + tr * NTILE + tc;
            int idx = atomicAdd(&cnt[list], 1);      // idx < 512 guaranteed
            lists[list * LIST_CAP + idx] = pack;
        }
    }
}

// ---- kernel 2: gather, branch-free inner loop. One block per
// (b, tile, 16-row band): 4096 blocks. Thread owns 4 rows x 1 col.
// Stage pass pre-filters candidates by row overlap; main loop does
// unconditional clamped loads + masked FMA so loads pipeline freely. ----
__global__ __launch_bounds__(256) void gather_kernel(
        const float* __restrict__ logits,
        const int* __restrict__ cnt,
        const unsigned* __restrict__ lists,
        float* __restrict__ out) {
    __shared__ unsigned sl[LIST_CAP];
    __shared__ int s_m;

    int blk  = blockIdx.x;
    int band = blk & 3;                      // 16-row band within tile
    int list = blk >> 2;                     // b*64 + tr*8 + tc
    int b  = list >> 6;
    int tr = (list >> 3) & 7;
    int tc = list & 7;
    int R0 = tr * 64 + band * 16;            // first global row of this block

    if (threadIdx.x == 0) s_m = 0;
    __syncthreads();

    int n = cnt[list];                       // <= 512 by construction
    for (int i = threadIdx.x; i < n; i += 256) {
        unsigned e = lists[list * LIST_CAP + i];
        int ch = (e >> 10) & 511;
        if (ch <= R0 + 15 && ch + 63 >= R0)  // patch overlaps my 16 rows
            sl[atomicAdd(&s_m, 1)] = e;
    }
    __syncthreads();
    int m = s_m;

    int lane = threadIdx.x & 63;             // column within tile
    int w    = threadIdx.x >> 6;             // wave id: 4-row group
    int gcol = tc * 64 + lane;               // global column
    int row0 = R0 + w * 4;                   // first of my 4 rows

    float sum0 = 0.f, sum1 = 0.f, sum2 = 0.f, sum3 = 0.f;
    float cc0  = 0.f, cc1  = 0.f, cc2  = 0.f, cc3  = 0.f;

#pragma unroll 4
    for (int i = 0; i < m; ++i) {
        unsigned e = __builtin_amdgcn_readfirstlane(sl[i]);  // scalar decode
        int k  = e & 1023;
        int ch = (e >> 10) & 511;
        int cw = (e >> 19) & 511;

        int dc = gcol - cw;                              // per-lane col in patch
        float colw = ((unsigned)dc < 64u) ? 1.0f : 0.0f;
        int dcc = min(max(dc, 0), 63);                   // v_med3: safe col

        int dr0 = row0 - ch;                             // uniform row in patch
        const float* p = logits + ((size_t)(b * NPATCH + k) << 12) + dcc;

        int r0 = min(max(dr0 + 0, 0), 63);               // clamped safe rows
        int r1 = min(max(dr0 + 1, 0), 63);
        int r2 = min(max(dr0 + 2, 0), 63);
        int r3 = min(max(dr0 + 3, 0), 63);
        float v0 = p[r0 << 6];                           // always load; L2 eats
        float v1 = p[r1 << 6];                           //   the clamp dups
        float v2 = p[r2 << 6];
        float v3 = p[r3 << 6];
        float w0 = ((unsigned)(dr0 + 0) < 64u) ? colw : 0.0f;
        float w1 = ((unsigned)(dr0 + 1) < 64u) ? colw : 0.0f;
        float w2 = ((unsigned)(dr0 + 2) < 64u) ? colw : 0.0f;
        float w3 = ((unsigned)(dr0 + 3) < 64u) ? colw : 0.0f;
        sum0 += v0 * w0;  cc0 += w0;
        sum1 += v1 * w1;  cc1 += w1;
        sum2 += v2 * w2;  cc2 += w2;
        sum3 += v3 * w3;  cc3 += w3;
    }

    size_t obase = ((size_t)b * RES + row0) * RES + gcol;
    __builtin_nontemporal_store(sum0 / fmaxf(cc0, 1.0f), &out[obase + 0 * RES]);
    __builtin_nontemporal_store(sum1 / fmaxf(cc1, 1.0f), &out[obase + 1 * RES]);
    __builtin_nontemporal_store(sum2 / fmaxf(cc2, 1.0f), &out[obase + 2 * RES]);
    __builtin_nontemporal_store(sum3 / fmaxf(cc3, 1.0f), &out[obase + 3 * RES]);
}

extern "C" void kernel_launch(void* const* d_in, const int* in_sizes, int n_in,
                              void* d_out, int out_size, void* d_ws, size_t ws_size,
                              hipStream_t stream) {
    const float* logits = (const float*)d_in[0];  // [16,512,1,64,64] f32
    const int*   coords = (const int*)d_in[1];    // [16,512,2] i32
    float* out = (float*)d_out;                   // [16,1,512,512] f32

    // ws layout: [0,4KB) list counters | [4KB, 4KB+2MB) packed lists
    int*      cnt   = (int*)d_ws;
    unsigned* lists = (unsigned*)((char*)d_ws + 4096);

    hipMemsetAsync(cnt, 0, NLISTS * sizeof(int), stream);
    bin_kernel<<<(BATCH * NPATCH + 255) / 256, 256, 0, stream>>>(coords, cnt, lists);
    gather_kernel<<<NLISTS * 4, 256, 0, stream>>>(logits, cnt, lists, out);
}

// Round 6
// 210.515 us; speedup vs baseline: 2.1068x; 1.0434x over previous
//
#include <hip/hip_runtime.h>

#define RES 512
#define PS 64
#define NPATCH 512
#define BATCH 16
#define NTILE 8                              // 8x8 tiles of 64x64 per image

// Single fused kernel. One block per (b, 64x64 tile, 16-row band): 4096 blocks.
// Stage: block scans its batch's 512 coords (64KB total, L2-broadcast across
// blocks) and keeps patches overlapping its 16x64 region in LDS.
// Gather: thread owns 4 rows x 1 col; branch-free clamped loads + masked FMA;
// logits read ~once device-wide, output written exactly once. No workspace.
__global__ __launch_bounds__(256) void fused_gather_kernel(
        const float* __restrict__ logits,
        const int*   __restrict__ coords,
        float* __restrict__ out) {
    __shared__ unsigned sl[NPATCH];          // worst case: every patch overlaps
    __shared__ int s_m;

    int blk  = blockIdx.x;
    int band = blk & 3;                      // 16-row band within tile
    int list = blk >> 2;                     // b*64 + tr*8 + tc
    int b  = list >> 6;
    int tr = (list >> 3) & 7;
    int tc = list & 7;
    int R0 = tr * 64 + band * 16;            // first global row of this block
    int C0 = tc * 64;                        // first global col of this block

    if (threadIdx.x == 0) s_m = 0;
    __syncthreads();

    // ---- stage: filter this batch's patches to my 16x64 region ----
    const int2* cb = (const int2*)(coords + (size_t)b * NPATCH * 2);
    for (int k = threadIdx.x; k < NPATCH; k += 256) {
        int2 c = cb[k];                      // (ch, cw), each in [0,448]
        int ch = c.x, cw = c.y;
        // patch rows [ch,ch+63] hit [R0,R0+15]; cols [cw,cw+63] hit [C0,C0+63]
        if (ch <= R0 + 15 && ch >= R0 - 63 && cw <= C0 + 63 && cw >= C0 - 63) {
            unsigned pack = (unsigned)k | ((unsigned)ch << 10) | ((unsigned)cw << 19);
            sl[atomicAdd(&s_m, 1)] = pack;
        }
    }
    __syncthreads();
    int m = s_m;

    // ---- gather ----
    int lane = threadIdx.x & 63;             // column within tile
    int w    = threadIdx.x >> 6;             // wave id: 4-row group
    int gcol = C0 + lane;                    // global column
    int row0 = R0 + w * 4;                   // first of my 4 rows

    float sum0 = 0.f, sum1 = 0.f, sum2 = 0.f, sum3 = 0.f;
    float cc0  = 0.f, cc1  = 0.f, cc2  = 0.f, cc3  = 0.f;

#pragma unroll 8
    for (int i = 0; i < m; ++i) {
        unsigned e = __builtin_amdgcn_readfirstlane(sl[i]);  // scalar decode
        int k  = e & 1023;
        int ch = (e >> 10) & 511;
        int cw = (e >> 19) & 511;

        int dc = gcol - cw;                              // per-lane col in patch
        float colw = ((unsigned)dc < 64u) ? 1.0f : 0.0f;
        int dcc = min(max(dc, 0), 63);                   // v_med3: safe col

        int dr0 = row0 - ch;                             // uniform row in patch
        const float* p = logits + ((size_t)(b * NPATCH + k) << 12) + dcc;

        int r0 = min(max(dr0 + 0, 0), 63);               // clamped safe rows
        int r1 = min(max(dr0 + 1, 0), 63);
        int r2 = min(max(dr0 + 2, 0), 63);
        int r3 = min(max(dr0 + 3, 0), 63);
        float v0 = p[r0 << 6];                           // always load; L2 eats
        float v1 = p[r1 << 6];                           //   the clamp dups
        float v2 = p[r2 << 6];
        float v3 = p[r3 << 6];
        float w0 = ((unsigned)(dr0 + 0) < 64u) ? colw : 0.0f;
        float w1 = ((unsigned)(dr0 + 1) < 64u) ? colw : 0.0f;
        float w2 = ((unsigned)(dr0 + 2) < 64u) ? colw : 0.0f;
        float w3 = ((unsigned)(dr0 + 3) < 64u) ? colw : 0.0f;
        sum0 += v0 * w0;  cc0 += w0;
        sum1 += v1 * w1;  cc1 += w1;
        sum2 += v2 * w2;  cc2 += w2;
        sum3 += v3 * w3;  cc3 += w3;
    }

    size_t obase = ((size_t)b * RES + row0) * RES + gcol;
    __builtin_nontemporal_store(sum0 / fmaxf(cc0, 1.0f), &out[obase + 0 * RES]);
    __builtin_nontemporal_store(sum1 / fmaxf(cc1, 1.0f), &out[obase + 1 * RES]);
    __builtin_nontemporal_store(sum2 / fmaxf(cc2, 1.0f), &out[obase + 2 * RES]);
    __builtin_nontemporal_store(sum3 / fmaxf(cc3, 1.0f), &out[obase + 3 * RES]);
}

extern "C" void kernel_launch(void* const* d_in, const int* in_sizes, int n_in,
                              void* d_out, int out_size, void* d_ws, size_t ws_size,
                              hipStream_t stream) {
    const float* logits = (const float*)d_in[0];  // [16,512,1,64,64] f32
    const int*   coords = (const int*)d_in[1];    // [16,512,2] i32
    float* out = (float*)d_out;                   // [16,1,512,512] f32
    (void)d_ws; (void)ws_size;

    fused_gather_kernel<<<BATCH * NTILE * NTILE * 4, 256, 0, stream>>>(logits, coords, out);
}

// Round 7
// 199.311 us; speedup vs baseline: 2.2252x; 1.0562x over previous
//
#include <hip/hip_runtime.h>

#define RES 512
#define PS 64
#define NPATCH 512
#define BATCH 16
#define NTILE 8                              // 8x8 tiles of 64x64 per image

// Single fused kernel. One block per (b, 64x64 tile, 16-row band): 4096 blocks.
// Stage: block scans its batch's 512 coords (64KB, L2/L3-broadcast) and keeps
// patches overlapping its 16x64 region in LDS, padded to a multiple of 8 with
// column-invalid dummies so the hot loop has no remainder.
// Gather: thread owns 4 rows x 1 col; branch-free clamped loads + masked FMA.
__global__ __launch_bounds__(256) void fused_gather_kernel(
        const float* __restrict__ logits,
        const int*   __restrict__ coords,
        float* __restrict__ out) {
    __shared__ unsigned sl[NPATCH + 8];
    __shared__ int s_m;

    int blk  = blockIdx.x;
    int band = blk & 3;                      // 16-row band within tile
    int list = blk >> 2;                     // b*64 + tr*8 + tc
    int b  = list >> 6;
    int tr = (list >> 3) & 7;
    int tc = list & 7;
    int R0 = tr * 64 + band * 16;            // first global row of this block
    int C0 = tc * 64;                        // first global col of this block

    if (threadIdx.x == 0) s_m = 0;
    __syncthreads();

    // ---- stage: filter this batch's patches to my 16x64 region ----
    const int2* cb = (const int2*)(coords + (size_t)b * NPATCH * 2);
    for (int k = threadIdx.x; k < NPATCH; k += 256) {
        int2 c = cb[k];                      // (ch, cw), each in [0,448]
        int ch = c.x, cw = c.y;
        if (ch <= R0 + 15 && ch >= R0 - 63 && cw <= C0 + 63 && cw >= C0 - 63) {
            unsigned pack = (unsigned)k | ((unsigned)ch << 10) | ((unsigned)cw << 19);
            sl[atomicAdd(&s_m, 1)] = pack;
        }
    }
    __syncthreads();
    int m  = s_m;
    int mp = (m + 7) & ~7;                   // pad to multiple of 8
    // dummy: cw9=(C0+256)&511 makes (gcol-cw) >= 64 (unsigned) for EVERY lane
    // of this block -> colw = 0 -> contributes nothing; k=0,ch=0 loads are
    // harmless in-bounds reads of patch 0.
    if (threadIdx.x < (unsigned)(mp - m))
        sl[m + threadIdx.x] = ((unsigned)((C0 + 256) & 511)) << 19;
    __syncthreads();

    // ---- gather ----
    int lane = threadIdx.x & 63;             // column within tile
    int w    = threadIdx.x >> 6;             // wave id: 4-row group
    int gcol4 = (C0 + lane) << 2;            // global column, byte-scaled
    int row0 = R0 + w * 4;                   // first of my 4 rows

    float sum0 = 0.f, sum1 = 0.f, sum2 = 0.f, sum3 = 0.f;
    float cc0  = 0.f, cc1  = 0.f, cc2  = 0.f, cc3  = 0.f;

#pragma unroll 8
    for (int i = 0; i < mp; ++i) {
        unsigned e = __builtin_amdgcn_readfirstlane(sl[i]);  // scalar decode
        int k   = e & 1023;
        int ch  = (e >> 10) & 511;
        int cw4 = ((e >> 19) & 511) << 2;

        int t = gcol4 - cw4;                             // byte col offset in patch
        float colw = ((unsigned)t < 256u) ? 1.0f : 0.0f;
        int voff = min(max(t, 0), 252);                  // v_med3: safe byte col

        int dr0 = row0 - ch;                             // uniform row in patch
        const char* p = (const char*)(logits + ((size_t)((b << 9) + k) << 12));

        int r0 = min(max(dr0 + 0, 0), 63) << 8;          // clamped byte row offs
        int r1 = min(max(dr0 + 1, 0), 63) << 8;
        int r2 = min(max(dr0 + 2, 0), 63) << 8;
        int r3 = min(max(dr0 + 3, 0), 63) << 8;
        float v0 = *(const float*)(p + r0 + voff);       // always load; L2 eats
        float v1 = *(const float*)(p + r1 + voff);       //   the clamp dups
        float v2 = *(const float*)(p + r2 + voff);
        float v3 = *(const float*)(p + r3 + voff);
        float w0 = ((unsigned)(dr0 + 0) < 64u) ? colw : 0.0f;
        float w1 = ((unsigned)(dr0 + 1) < 64u) ? colw : 0.0f;
        float w2 = ((unsigned)(dr0 + 2) < 64u) ? colw : 0.0f;
        float w3 = ((unsigned)(dr0 + 3) < 64u) ? colw : 0.0f;
        sum0 += v0 * w0;  cc0 += w0;
        sum1 += v1 * w1;  cc1 += w1;
        sum2 += v2 * w2;  cc2 += w2;
        sum3 += v3 * w3;  cc3 += w3;
    }

    size_t obase = ((size_t)b * RES + row0) * RES + (gcol4 >> 2);
    __builtin_nontemporal_store(sum0 / fmaxf(cc0, 1.0f), &out[obase + 0 * RES]);
    __builtin_nontemporal_store(sum1 / fmaxf(cc1, 1.0f), &out[obase + 1 * RES]);
    __builtin_nontemporal_store(sum2 / fmaxf(cc2, 1.0f), &out[obase + 2 * RES]);
    __builtin_nontemporal_store(sum3 / fmaxf(cc3, 1.0f), &out[obase + 3 * RES]);
}

extern "C" void kernel_launch(void* const* d_in, const int* in_sizes, int n_in,
                              void* d_out, int out_size, void* d_ws, size_t ws_size,
                              hipStream_t stream) {
    const float* logits = (const float*)d_in[0];  // [16,512,1,64,64] f32
    const int*   coords = (const int*)d_in[1];    // [16,512,2] i32
    float* out = (float*)d_out;                   // [16,1,512,512] f32
    (void)d_ws; (void)ws_size;

    fused_gather_kernel<<<BATCH * NTILE * NTILE * 4, 256, 0, stream>>>(logits, coords, out);
}